// Round 7
// baseline (1757.928 us; speedup 1.0000x reference)
//
#include <hip/hip_runtime.h>
#include <stdint.h>
#include <math.h>

#define T_SIM 500
#define NB    64
#define NIN   1024
#define NHID  1024
#define NOUT  10
#define KSRM  77     // SRM kernel taps 0..76 (srm[0] == 0)
#define CHUNK 16     // batches per pipeline stage (4 stages)
#define FTT   64     // t-tile in k_fir
#define FSTG  140    // staged rows = FTT + 76

// Reference builds kernels in python f64 then rounds to fp32; we reproduce the
// exact fp32 tap values and do all accumulation in f64 (verified: absmax 0).
__device__ __forceinline__ double srm_tap(int k) {
  double u = (double)k / 10.0;
  double v = u * exp(1.0 - u);
  return (double)(float)v;
}
__device__ __forceinline__ double ref_tap(int j) {
  double v = (-20.0 * (double)j) * exp(1.0 - (double)j);
  return (double)(float)v;
}

// ---------------------------------------------------------------------------
// K0: pack binary input spikes x[b][i][t] (fp32 0/1) -> bits [b][t][16 x u64]
__global__ __launch_bounds__(64)
void k_pack(const float* __restrict__ x, unsigned long long* __restrict__ bits) {
  const int b = blockIdx.x, ig = blockIdx.y, tc = blockIdx.z;
  const int lane = threadIdx.x;
  const float* xr = x + ((size_t)b * NIN + ig * 64 + lane) * T_SIM;
  const int t0 = tc * 100;
  for (int t = t0; t < t0 + 100; t += 4) {
    const float4 v = *(const float4*)(xr + t);
    unsigned long long m0 = __ballot(v.x > 0.5f);
    unsigned long long m1 = __ballot(v.y > 0.5f);
    unsigned long long m2 = __ballot(v.z > 0.5f);
    unsigned long long m3 = __ballot(v.w > 0.5f);
    if (lane == 0) {
      unsigned long long* w = bits + (size_t)(b * T_SIM + t) * 16 + ig;
      w[0] = m0; w[16] = m1; w[32] = m2; w[48] = m3;
    }
  }
}

// ---------------------------------------------------------------------------
// K0b: W1[o][i] -> W1T[i][o] fp32, tiled 64x64 through LDS.
__global__ __launch_bounds__(256)
void k_transpose(const float* __restrict__ W1, float* __restrict__ W1T) {
  __shared__ float tile[64][65];
  const int bo = blockIdx.x * 64, bi = blockIdx.y * 64;
  for (int k = threadIdx.x; k < 4096; k += 256) {
    int r = k >> 6, c = k & 63;
    tile[r][c] = W1[(size_t)(bo + r) * NIN + bi + c];
  }
  __syncthreads();
  for (int k = threadIdx.x; k < 4096; k += 256) {
    int r = k >> 6, c = k & 63;
    W1T[(size_t)(bi + r) * NHID + bo + c] = tile[c][r];
  }
}

// ---------------------------------------------------------------------------
// K1: dense1 sparse gather (v3, proven): 8 loads in flight, accumulator
// mapping (g&3) bitwise-identical to R6. Non-temporal a1c stores.
// grid (CHUNK*500, 2), block 128.
__global__ __launch_bounds__(128)
void k_dense1(const uint32_t* __restrict__ bits, const float* __restrict__ W1T,
              double* __restrict__ a1c, int col_base) {
  __shared__ int list[NIN];
  __shared__ int nact_s;
  const int col_loc = blockIdx.x;
  const int tid = threadIdx.x;
  if (tid < 32) {
    uint32_t w = bits[(size_t)(col_base + col_loc) * 32 + tid];
    int c = __popc(w);
    int p = c;
#pragma unroll
    for (int d = 1; d < 32; d <<= 1) {
      int q = __shfl_up(p, d);
      if (tid >= d) p += q;
    }
    int excl = p - c;
    while (w) {
      const int j = __ffs(w) - 1;
      w &= w - 1;
      list[excl++] = tid * 32 + j;   // i ascending overall
    }
    if (tid == 31) nact_s = excl;
  }
  __syncthreads();
  const int n = nact_s;
  const int o = blockIdx.y * 512 + tid * 4;
  double ax[4] = {0,0,0,0}, ay[4] = {0,0,0,0};
  double az[4] = {0,0,0,0}, aw[4] = {0,0,0,0};
  float4 L[8];
  int g = 0;
  if (n >= 8) {
#pragma unroll
    for (int r = 0; r < 8; ++r)
      L[r] = *(const float4*)(W1T + (size_t)list[r] * NHID + o);
    for (g = 0; g + 16 <= n; g += 8) {
      float4 Nb[8];
#pragma unroll
      for (int r = 0; r < 8; ++r)
        Nb[r] = *(const float4*)(W1T + (size_t)list[g + 8 + r] * NHID + o);
#pragma unroll
      for (int r = 0; r < 8; ++r) {
        const int s = r & 3;   // (g+r)&3 == r&3 since g%8==0
        ax[s] += (double)L[r].x; ay[s] += (double)L[r].y;
        az[s] += (double)L[r].z; aw[s] += (double)L[r].w;
      }
#pragma unroll
      for (int r = 0; r < 8; ++r) L[r] = Nb[r];
    }
#pragma unroll
    for (int r = 0; r < 8; ++r) {
      const int s = r & 3;
      ax[s] += (double)L[r].x; ay[s] += (double)L[r].y;
      az[s] += (double)L[r].z; aw[s] += (double)L[r].w;
    }
    g += 8;
  }
  for (; g < n; ++g) {
    const float4 wv = *(const float4*)(W1T + (size_t)list[g] * NHID + o);
    const int s = g & 3;
    ax[s] += (double)wv.x; ay[s] += (double)wv.y;
    az[s] += (double)wv.z; aw[s] += (double)wv.w;
  }
  double* dst = a1c + (size_t)col_loc * NHID + o;
  __builtin_nontemporal_store((ax[0] + ax[1]) + (ax[2] + ax[3]), dst + 0);
  __builtin_nontemporal_store((ay[0] + ay[1]) + (ay[2] + ay[3]), dst + 1);
  __builtin_nontemporal_store((az[0] + az[1]) + (az[2] + az[3]), dst + 2);
  __builtin_nontemporal_store((aw[0] + aw[1]) + (aw[2] + aw[3]), dst + 3);
}

// ---------------------------------------------------------------------------
// K2a: k_fir (v12) -- pure t-parallel 77-tap SRM FIR, f64, a1c -> Y.
// ps1's FIR/scan coupling (6 FIR waves + 1 scan wave, 42 serial barriers)
// is DELETED: this kernel has no serial section and one barrier.
// Block 256 thr = (tq 0..7) x (n 0..31); covers one (b, 32-n group, 64-t
// tile). Stage x[T0-76 .. T0+63][32n] in LDS (35,840 B + 640 taps ->
// 4 blocks/CU). Each thread: 8 consecutive t outputs, full 77-tap loop
// (taps broadcast from LDS; 8 ds_read_b64 at imm offsets per k).
// Summation: single f64 acc, k ascending -- an f64 reorder vs v8's 4-partial
// scheme (~1e-13), nine orders below the empirically-proven >=1e-5 margin.
// grid (8 t-tiles, 32 ng, CHUNK b).
__global__ __launch_bounds__(256)
void k_fir(const double* __restrict__ a1c, double* __restrict__ Y) {
  __shared__ double S[FSTG * 32];
  __shared__ double TB[80];
  const int tt = blockIdx.x;      // 0..7
  const int ng = blockIdx.y;      // 0..31
  const int b  = blockIdx.z;      // 0..CHUNK-1
  const int tid = threadIdx.x;
  const int T0 = tt * FTT;
  const double* __restrict__ abase = a1c + (size_t)b * T_SIM * NHID + ng * 32;
  if (tid < 80) TB[tid] = (tid <= 76) ? srm_tap(tid) : 0.0;
  for (int e = tid; e < FSTG * 32; e += 256) {
    const int r = e >> 5, n = e & 31;
    const int t = T0 - 76 + r;
    double v = 0.0;
    if (t >= 0 && t < T_SIM) v = abase[(size_t)t * NHID + n];
    S[r * 32 + n] = v;
  }
  __syncthreads();
  const int n = tid & 31, tq = tid >> 5;   // tq 0..7
  double acc[8] = {0, 0, 0, 0, 0, 0, 0, 0};
  const int base = (tq * 8 + 76) * 32 + n;
  for (int k = 0; k <= 76; ++k) {
    const double tap = TB[k];
    const double* Sp = &S[base - k * 32];
#pragma unroll
    for (int r = 0; r < 8; ++r)
      acc[r] += tap * Sp[r * 32];
  }
  double* ybase = Y + (size_t)b * T_SIM * NHID + ng * 32 + n;
  const int tb = T0 + tq * 8;
#pragma unroll
  for (int r = 0; r < 8; ++r)
    if (tb + r < T_SIM)
      __builtin_nontemporal_store(acc[r], &ybase[(size_t)(tb + r) * NHID]);
}

// ---------------------------------------------------------------------------
// K2b: k_scan (v12) -- refractory scan, one thread per (b, n), 500 serial
// steps. 65,536 independent chains per chunk run concurrently (vs v8's ONE
// scan wave per block gated by 42 barriers). Per step: load Y (coalesced
// 512 B/wave), 10-tap refractory chain in the EXACT v8 order (j=10..1,
// refk[j]*(double)bit), threshold, ballot -> u64 spike-mask store.
// BW-bound on the Y read (~65 MB/chunk). grid (16 n-slices, CHUNK b),
// block 64 (1 wave) -> 256 blocks, 1/CU.
__global__ __launch_bounds__(64)
void k_scan(const double* __restrict__ Y, uint32_t* __restrict__ s1w,
            int b_base) {
  const int n0 = blockIdx.x * 64;
  const int b  = blockIdx.y;
  const int lane = threadIdx.x;
  const double* __restrict__ ybase = Y + (size_t)b * T_SIM * NHID + n0 + lane;
  unsigned long long* __restrict__ sbase = (unsigned long long*)
      (s1w + (size_t)(b_base + b) * T_SIM * 32 + (n0 >> 5));
  double refk[11];
#pragma unroll
  for (int j = 1; j <= 10; ++j) refk[j] = ref_tap(j);
  uint32_t smask = 0;
#pragma unroll 4
  for (int t = 0; t < T_SIM; ++t) {
    double u = ybase[(size_t)t * NHID];
#pragma unroll
    for (int j = 10; j >= 1; --j)
      u += refk[j] * (double)((smask >> (j - 1)) & 1u);
    const bool sp = (u >= 10.0);
    smask = (smask << 1) | (sp ? 1u : 0u);
    const unsigned long long bm = __ballot(sp);
    if (lane == 0) sbase[(size_t)t * 16] = bm;
  }
}

// ---------------------------------------------------------------------------
// K3: dense2 sparse gather from s1 u32 masks, W2 fp32 in LDS, f64 acc.
__global__ __launch_bounds__(256)
void k_dense2(const uint32_t* __restrict__ s1w,
              const float* __restrict__ W2, double* __restrict__ a2) {
  __shared__ float w2t[NHID * NOUT];  // 40 KB, [i][o]
  for (int k = threadIdx.x; k < NHID * NOUT; k += 256) {
    const int o = k >> 10, i = k & 1023;
    w2t[i * NOUT + o] = W2[k];
  }
  __syncthreads();
  const int col = blockIdx.x * 256 + threadIdx.x;  // 0..31999
  double acc[NOUT];
#pragma unroll
  for (int o = 0; o < NOUT; ++o) acc[o] = 0.0;
  const uint32_t* w = s1w + (size_t)col * 32;
  for (int wi = 0; wi < 32; ++wi) {
    uint32_t m = w[wi];
    const int ibase = wi * 32;
    while (m) {
      const int j = __ffs(m) - 1;
      m &= m - 1;
      const float* row = &w2t[(ibase + j) * NOUT];
#pragma unroll
      for (int o = 0; o < NOUT; ++o) acc[o] += (double)row[o];
    }
  }
  double* outp = a2 + (size_t)col * NOUT;
#pragma unroll
  for (int o = 0; o < NOUT; ++o) outp[o] = acc[o];
}

// ---------------------------------------------------------------------------
// K4: FUSED psp2 + spike2, one block per batch; whole [500][10] in LDS.
__global__ __launch_bounds__(256)
void k_l2(const double* __restrict__ a2, float* __restrict__ out) {
  __shared__ double S[T_SIM * NOUT];
  __shared__ double Y[T_SIM * NOUT];
  __shared__ double srm[KSRM];
  const int b = blockIdx.x, tid = threadIdx.x;
  if (tid < KSRM) srm[tid] = srm_tap(tid);
  for (int i = tid; i < T_SIM * NOUT; i += 256)
    S[i] = a2[(size_t)b * T_SIM * NOUT + i];
  __syncthreads();
  for (int i = tid; i < T_SIM * NOUT; i += 256) {
    const int t = i / 10, o = i - t * 10;
    const int kmax = (t < KSRM - 1) ? t : (KSRM - 1);
    double acc = 0.0;
    for (int k = 0; k <= kmax; ++k)
      acc += srm[k] * S[(t - k) * 10 + o];
    Y[i] = acc;
  }
  __syncthreads();
  if (tid < NOUT) {
    double refk[11];
#pragma unroll
    for (int j = 1; j <= 10; ++j) refk[j] = ref_tap(j);
    uint32_t smask = 0;
    float* op = out + ((size_t)b * NOUT + tid) * T_SIM;
    for (int t = 0; t < T_SIM; ++t) {
      double u = Y[t * 10 + tid];
#pragma unroll
      for (int j = 10; j >= 1; --j)
        u += refk[j] * (double)((smask >> (j - 1)) & 1u);
      const bool sp = (u >= 10.0);
      smask = (smask << 1) | (sp ? 1u : 0u);
      op[t] = sp ? 1.0f : 0.0f;
    }
  }
}

// ---------------------------------------------------------------------------
extern "C" void kernel_launch(void* const* d_in, const int* in_sizes, int n_in,
                              void* d_out, int out_size, void* d_ws, size_t ws_size,
                              hipStream_t stream) {
  const float* x  = (const float*)d_in[0];   // [64][1024][500]
  const float* W1 = (const float*)d_in[1];   // [1024][1024]
  const float* W2 = (const float*)d_in[2];   // [10][1024]
  float* out = (float*)d_out;                // [64][10][500]

  char* ws = (char*)d_ws;
  unsigned long long* bits1 = (unsigned long long*)(ws);   // 4,096,000
  float*  W1T = (float*)(ws + 4096000);                    // 4,194,304
  double* a1c = (double*)(ws + 8290304);                   // 65,536,000 (16 b)
  double* Yb  = (double*)(ws + 73826304);                  // 65,536,000 (16 b)
  uint32_t* s1w = (uint32_t*)(ws + 139362304);             // 4,096,000
  double* a2  = (double*)(ws + 143458304);                 // 2,560,000
  // total ws use: 146,018,304 B (identical footprint to the proven v8)

  hipLaunchKernelGGL(k_pack, dim3(NB, 16, 5), dim3(64), 0, stream, x, bits1);
  hipLaunchKernelGGL(k_transpose, dim3(16, 16), dim3(256), 0, stream, W1, W1T);

  for (int c = 0; c < NB / CHUNK; ++c) {
    hipLaunchKernelGGL(k_dense1, dim3(CHUNK * T_SIM, 2), dim3(128), 0, stream,
                       (const uint32_t*)bits1, W1T, a1c, c * CHUNK * T_SIM);
    hipLaunchKernelGGL(k_fir, dim3(8, 32, CHUNK), dim3(256), 0, stream,
                       a1c, Yb);
    hipLaunchKernelGGL(k_scan, dim3(16, CHUNK), dim3(64), 0, stream,
                       Yb, s1w, c * CHUNK);
  }

  hipLaunchKernelGGL(k_dense2, dim3(125), dim3(256), 0, stream, s1w, W2, a2);
  hipLaunchKernelGGL(k_l2, dim3(NB), dim3(256), 0, stream, a2, out);
}

// Round 8
// 1548.081 us; speedup vs baseline: 1.1356x; 1.1356x over previous
//
#include <hip/hip_runtime.h>
#include <stdint.h>
#include <math.h>

#define T_SIM 500
#define NB    64
#define NIN   1024
#define NHID  1024
#define NOUT  10
#define KSRM  77     // SRM kernel taps 0..76 (srm[0] == 0)
#define CHUNK 16     // batches per pipeline stage (4 stages)
#define FTT   64     // t-tile in k_fir
#define FSTG  140    // staged rows = FTT + 76
#define SPF   20     // k_scan prefetch depth (500 % 20 == 0)

// Reference builds kernels in python f64 then rounds to fp32; we reproduce the
// exact fp32 tap values and do all accumulation in f64 (verified: absmax 0).
__device__ __forceinline__ double srm_tap(int k) {
  double u = (double)k / 10.0;
  double v = u * exp(1.0 - u);
  return (double)(float)v;
}
__device__ __forceinline__ double ref_tap(int j) {
  double v = (-20.0 * (double)j) * exp(1.0 - (double)j);
  return (double)(float)v;
}

// ---------------------------------------------------------------------------
// K0: pack binary input spikes x[b][i][t] (fp32 0/1) -> bits [b][t][16 x u64]
__global__ __launch_bounds__(64)
void k_pack(const float* __restrict__ x, unsigned long long* __restrict__ bits) {
  const int b = blockIdx.x, ig = blockIdx.y, tc = blockIdx.z;
  const int lane = threadIdx.x;
  const float* xr = x + ((size_t)b * NIN + ig * 64 + lane) * T_SIM;
  const int t0 = tc * 100;
  for (int t = t0; t < t0 + 100; t += 4) {
    const float4 v = *(const float4*)(xr + t);
    unsigned long long m0 = __ballot(v.x > 0.5f);
    unsigned long long m1 = __ballot(v.y > 0.5f);
    unsigned long long m2 = __ballot(v.z > 0.5f);
    unsigned long long m3 = __ballot(v.w > 0.5f);
    if (lane == 0) {
      unsigned long long* w = bits + (size_t)(b * T_SIM + t) * 16 + ig;
      w[0] = m0; w[16] = m1; w[32] = m2; w[48] = m3;
    }
  }
}

// ---------------------------------------------------------------------------
// K0b: W1[o][i] -> W1T[i][o] fp32, tiled 64x64 through LDS.
__global__ __launch_bounds__(256)
void k_transpose(const float* __restrict__ W1, float* __restrict__ W1T) {
  __shared__ float tile[64][65];
  const int bo = blockIdx.x * 64, bi = blockIdx.y * 64;
  for (int k = threadIdx.x; k < 4096; k += 256) {
    int r = k >> 6, c = k & 63;
    tile[r][c] = W1[(size_t)(bo + r) * NIN + bi + c];
  }
  __syncthreads();
  for (int k = threadIdx.x; k < 4096; k += 256) {
    int r = k >> 6, c = k & 63;
    W1T[(size_t)(bi + r) * NHID + bo + c] = tile[c][r];
  }
}

// ---------------------------------------------------------------------------
// K1: dense1 sparse gather (v3, proven): 8 loads in flight, accumulator
// mapping (g&3) bitwise-identical to R6. Non-temporal a1c stores.
// grid (CHUNK*500, 2), block 128.
__global__ __launch_bounds__(128)
void k_dense1(const uint32_t* __restrict__ bits, const float* __restrict__ W1T,
              double* __restrict__ a1c, int col_base) {
  __shared__ int list[NIN];
  __shared__ int nact_s;
  const int col_loc = blockIdx.x;
  const int tid = threadIdx.x;
  if (tid < 32) {
    uint32_t w = bits[(size_t)(col_base + col_loc) * 32 + tid];
    int c = __popc(w);
    int p = c;
#pragma unroll
    for (int d = 1; d < 32; d <<= 1) {
      int q = __shfl_up(p, d);
      if (tid >= d) p += q;
    }
    int excl = p - c;
    while (w) {
      const int j = __ffs(w) - 1;
      w &= w - 1;
      list[excl++] = tid * 32 + j;   // i ascending overall
    }
    if (tid == 31) nact_s = excl;
  }
  __syncthreads();
  const int n = nact_s;
  const int o = blockIdx.y * 512 + tid * 4;
  double ax[4] = {0,0,0,0}, ay[4] = {0,0,0,0};
  double az[4] = {0,0,0,0}, aw[4] = {0,0,0,0};
  float4 L[8];
  int g = 0;
  if (n >= 8) {
#pragma unroll
    for (int r = 0; r < 8; ++r)
      L[r] = *(const float4*)(W1T + (size_t)list[r] * NHID + o);
    for (g = 0; g + 16 <= n; g += 8) {
      float4 Nb[8];
#pragma unroll
      for (int r = 0; r < 8; ++r)
        Nb[r] = *(const float4*)(W1T + (size_t)list[g + 8 + r] * NHID + o);
#pragma unroll
      for (int r = 0; r < 8; ++r) {
        const int s = r & 3;   // (g+r)&3 == r&3 since g%8==0
        ax[s] += (double)L[r].x; ay[s] += (double)L[r].y;
        az[s] += (double)L[r].z; aw[s] += (double)L[r].w;
      }
#pragma unroll
      for (int r = 0; r < 8; ++r) L[r] = Nb[r];
    }
#pragma unroll
    for (int r = 0; r < 8; ++r) {
      const int s = r & 3;
      ax[s] += (double)L[r].x; ay[s] += (double)L[r].y;
      az[s] += (double)L[r].z; aw[s] += (double)L[r].w;
    }
    g += 8;
  }
  for (; g < n; ++g) {
    const float4 wv = *(const float4*)(W1T + (size_t)list[g] * NHID + o);
    const int s = g & 3;
    ax[s] += (double)wv.x; ay[s] += (double)wv.y;
    az[s] += (double)wv.z; aw[s] += (double)wv.w;
  }
  double* dst = a1c + (size_t)col_loc * NHID + o;
  __builtin_nontemporal_store((ax[0] + ax[1]) + (ax[2] + ax[3]), dst + 0);
  __builtin_nontemporal_store((ay[0] + ay[1]) + (ay[2] + ay[3]), dst + 1);
  __builtin_nontemporal_store((az[0] + az[1]) + (az[2] + az[3]), dst + 2);
  __builtin_nontemporal_store((aw[0] + aw[1]) + (aw[2] + aw[3]), dst + 3);
}

// ---------------------------------------------------------------------------
// K2a: k_fir v13 -- t-parallel 77-tap SRM FIR with SLIDING-WINDOW registers.
// v12 issued 693 LDS instrs/thread (8 row-reads + 1 tap per k). Consecutive
// taps shift the row window by exactly 1, so the 8 rows live in a circular
// register file w[(r-k)&7] (indices static after full unroll): 161 LDS
// instrs/thread, same 616 FMAs in the SAME k-ascending order per acc[r] --
// bitwise-identical to v12 (which passed absmax 0).
// Block 256 thr = (tq 0..7) x (n 0..31); LDS 36,480 B -> 4 blocks/CU.
// grid (8 t-tiles, 32 ng, CHUNK b).
__global__ __launch_bounds__(256)
void k_fir(const double* __restrict__ a1c, double* __restrict__ Y) {
  __shared__ double S[FSTG * 32];
  __shared__ double TB[80];
  const int tt = blockIdx.x;      // 0..7
  const int ng = blockIdx.y;      // 0..31
  const int b  = blockIdx.z;      // 0..CHUNK-1
  const int tid = threadIdx.x;
  const int T0 = tt * FTT;
  const double* __restrict__ abase = a1c + (size_t)b * T_SIM * NHID + ng * 32;
  if (tid < 80) TB[tid] = (tid <= 76) ? srm_tap(tid) : 0.0;
  for (int e = tid; e < FSTG * 32; e += 256) {
    const int r = e >> 5, n = e & 31;
    const int t = T0 - 76 + r;
    double v = 0.0;
    if (t >= 0 && t < T_SIM) v = abase[(size_t)t * NHID + n];
    S[r * 32 + n] = v;
  }
  __syncthreads();
  const int n = tid & 31, tq = tid >> 5;   // tq 0..7
  const int B = tq * 8 + 76;               // row of output t = T0+tq*8 (k=0)
  double acc[8] = {0, 0, 0, 0, 0, 0, 0, 0};
  double w[8];
#pragma unroll
  for (int r = 0; r < 8; ++r) w[r] = S[(B + r) * 32 + n];
#pragma unroll
  for (int k = 0; k <= 76; ++k) {
    const double tap = TB[k];
#pragma unroll
    for (int r = 0; r < 8; ++r)
      acc[r] += tap * w[(r - k) & 7];
    if (k < 76) w[(-k - 1) & 7] = S[(B - k - 1) * 32 + n];
  }
  double* ybase = Y + (size_t)b * T_SIM * NHID + ng * 32 + n;
  const int tb = T0 + tq * 8;
#pragma unroll
  for (int r = 0; r < 8; ++r)
    if (tb + r < T_SIM)
      __builtin_nontemporal_store(acc[r], &ybase[(size_t)(tb + r) * NHID]);
}

// ---------------------------------------------------------------------------
// K2b: k_scan v13 -- refractory scan with register prefetch depth 20.
// v12's loop issued each Y load INSIDE its step: a naked 500-deep dependent
// load chain at 1 wave/CU (228 us, VALUBusy 2.6%). All 500 loads are
// independent of the smask chain, so: preload yv[0..19]; step t consumes
// yv[p] and immediately issues the load for t+20 into the same register
// (static index via full unroll -- avoids scratch). Load latency is covered
// by 19 intervening steps. Chain order j=10..1 verbatim (bitwise-identical).
// grid (16 n-slices, CHUNK b), block 64 (1 wave).
__global__ __launch_bounds__(64)
void k_scan(const double* __restrict__ Y, uint32_t* __restrict__ s1w,
            int b_base) {
  const int n0 = blockIdx.x * 64;
  const int b  = blockIdx.y;
  const int lane = threadIdx.x;
  const double* __restrict__ ybase = Y + (size_t)b * T_SIM * NHID + n0 + lane;
  unsigned long long* __restrict__ sbase = (unsigned long long*)
      (s1w + (size_t)(b_base + b) * T_SIM * 32 + (n0 >> 5));
  double refk[11];
#pragma unroll
  for (int j = 1; j <= 10; ++j) refk[j] = ref_tap(j);
  double yv[SPF];
#pragma unroll
  for (int p = 0; p < SPF; ++p) yv[p] = ybase[(size_t)p * NHID];
  uint32_t smask = 0;
  for (int tb = 0; tb < T_SIM - SPF; tb += SPF) {
#pragma unroll
    for (int p = 0; p < SPF; ++p) {
      const int t = tb + p;
      double u = yv[p];
#pragma unroll
      for (int j = 10; j >= 1; --j)
        u += refk[j] * (double)((smask >> (j - 1)) & 1u);
      const bool sp = (u >= 10.0);
      smask = (smask << 1) | (sp ? 1u : 0u);
      const unsigned long long bm = __ballot(sp);
      if (lane == 0) sbase[(size_t)t * 16] = bm;
      yv[p] = ybase[(size_t)(t + SPF) * NHID];   // t+SPF <= 499 here
    }
  }
  // tail: last SPF steps, no prefetch
#pragma unroll
  for (int p = 0; p < SPF; ++p) {
    const int t = (T_SIM - SPF) + p;
    double u = yv[p];
#pragma unroll
    for (int j = 10; j >= 1; --j)
      u += refk[j] * (double)((smask >> (j - 1)) & 1u);
    const bool sp = (u >= 10.0);
    smask = (smask << 1) | (sp ? 1u : 0u);
    const unsigned long long bm = __ballot(sp);
    if (lane == 0) sbase[(size_t)t * 16] = bm;
  }
}

// ---------------------------------------------------------------------------
// K3: dense2 sparse gather from s1 u32 masks, W2 fp32 in LDS, f64 acc.
__global__ __launch_bounds__(256)
void k_dense2(const uint32_t* __restrict__ s1w,
              const float* __restrict__ W2, double* __restrict__ a2) {
  __shared__ float w2t[NHID * NOUT];  // 40 KB, [i][o]
  for (int k = threadIdx.x; k < NHID * NOUT; k += 256) {
    const int o = k >> 10, i = k & 1023;
    w2t[i * NOUT + o] = W2[k];
  }
  __syncthreads();
  const int col = blockIdx.x * 256 + threadIdx.x;  // 0..31999
  double acc[NOUT];
#pragma unroll
  for (int o = 0; o < NOUT; ++o) acc[o] = 0.0;
  const uint32_t* w = s1w + (size_t)col * 32;
  for (int wi = 0; wi < 32; ++wi) {
    uint32_t m = w[wi];
    const int ibase = wi * 32;
    while (m) {
      const int j = __ffs(m) - 1;
      m &= m - 1;
      const float* row = &w2t[(ibase + j) * NOUT];
#pragma unroll
      for (int o = 0; o < NOUT; ++o) acc[o] += (double)row[o];
    }
  }
  double* outp = a2 + (size_t)col * NOUT;
#pragma unroll
  for (int o = 0; o < NOUT; ++o) outp[o] = acc[o];
}

// ---------------------------------------------------------------------------
// K4: FUSED psp2 + spike2, one block per batch; whole [500][10] in LDS.
__global__ __launch_bounds__(256)
void k_l2(const double* __restrict__ a2, float* __restrict__ out) {
  __shared__ double S[T_SIM * NOUT];
  __shared__ double Y[T_SIM * NOUT];
  __shared__ double srm[KSRM];
  const int b = blockIdx.x, tid = threadIdx.x;
  if (tid < KSRM) srm[tid] = srm_tap(tid);
  for (int i = tid; i < T_SIM * NOUT; i += 256)
    S[i] = a2[(size_t)b * T_SIM * NOUT + i];
  __syncthreads();
  for (int i = tid; i < T_SIM * NOUT; i += 256) {
    const int t = i / 10, o = i - t * 10;
    const int kmax = (t < KSRM - 1) ? t : (KSRM - 1);
    double acc = 0.0;
    for (int k = 0; k <= kmax; ++k)
      acc += srm[k] * S[(t - k) * 10 + o];
    Y[i] = acc;
  }
  __syncthreads();
  if (tid < NOUT) {
    double refk[11];
#pragma unroll
    for (int j = 1; j <= 10; ++j) refk[j] = ref_tap(j);
    uint32_t smask = 0;
    float* op = out + ((size_t)b * NOUT + tid) * T_SIM;
    for (int t = 0; t < T_SIM; ++t) {
      double u = Y[t * 10 + tid];
#pragma unroll
      for (int j = 10; j >= 1; --j)
        u += refk[j] * (double)((smask >> (j - 1)) & 1u);
      const bool sp = (u >= 10.0);
      smask = (smask << 1) | (sp ? 1u : 0u);
      op[t] = sp ? 1.0f : 0.0f;
    }
  }
}

// ---------------------------------------------------------------------------
extern "C" void kernel_launch(void* const* d_in, const int* in_sizes, int n_in,
                              void* d_out, int out_size, void* d_ws, size_t ws_size,
                              hipStream_t stream) {
  const float* x  = (const float*)d_in[0];   // [64][1024][500]
  const float* W1 = (const float*)d_in[1];   // [1024][1024]
  const float* W2 = (const float*)d_in[2];   // [10][1024]
  float* out = (float*)d_out;                // [64][10][500]

  char* ws = (char*)d_ws;
  unsigned long long* bits1 = (unsigned long long*)(ws);   // 4,096,000
  float*  W1T = (float*)(ws + 4096000);                    // 4,194,304
  double* a1c = (double*)(ws + 8290304);                   // 65,536,000 (16 b)
  double* Yb  = (double*)(ws + 73826304);                  // 65,536,000 (16 b)
  uint32_t* s1w = (uint32_t*)(ws + 139362304);             // 4,096,000
  double* a2  = (double*)(ws + 143458304);                 // 2,560,000
  // total ws use: 146,018,304 B (identical footprint to the proven v8)

  hipLaunchKernelGGL(k_pack, dim3(NB, 16, 5), dim3(64), 0, stream, x, bits1);
  hipLaunchKernelGGL(k_transpose, dim3(16, 16), dim3(256), 0, stream, W1, W1T);

  for (int c = 0; c < NB / CHUNK; ++c) {
    hipLaunchKernelGGL(k_dense1, dim3(CHUNK * T_SIM, 2), dim3(128), 0, stream,
                       (const uint32_t*)bits1, W1T, a1c, c * CHUNK * T_SIM);
    hipLaunchKernelGGL(k_fir, dim3(8, 32, CHUNK), dim3(256), 0, stream,
                       a1c, Yb);
    hipLaunchKernelGGL(k_scan, dim3(16, CHUNK), dim3(64), 0, stream,
                       Yb, s1w, c * CHUNK);
  }

  hipLaunchKernelGGL(k_dense2, dim3(125), dim3(256), 0, stream, s1w, W2, a2);
  hipLaunchKernelGGL(k_l2, dim3(NB), dim3(256), 0, stream, a2, out);
}